// Round 3
// baseline (1411.116 us; speedup 1.0000x reference)
//
#include <hip/hip_runtime.h>

#define BATCH 1024
#define SEQ   144
#define DIM   192
#define NH    6
#define HD    32
#define SCALE 0.17677669529663687f  // 1/sqrt(32)

typedef __bf16 bf16x8 __attribute__((ext_vector_type(8)));
typedef __bf16 bf16x4 __attribute__((ext_vector_type(4)));
typedef float  f32x4  __attribute__((ext_vector_type(4)));

// ---- workspace layout (bytes) ----
#define WS_W1T   0         // bf16 [576][192]  w1t[c][k] = w1[k][c] (*SCALE for c<192)
#define WS_W2T   221184    // bf16 [192][192]  w2t[n][k] = w2[k][n]
#define WS_B1S   294912    // f32  [576]       b1 (*SCALE for c<192)
#define WS_BIAS  297216    // f32  [6][144][144]  bmT[h][key][query]
// total: 794880 B

// ---------------------------------------------------------------------------
// Prep: transpose/convert weights to bf16 B^T layout, build bias+mask table.
// ---------------------------------------------------------------------------
__global__ __launch_bounds__(256) void k_prep(
        const float* __restrict__ w1, const float* __restrict__ w2,
        const float* __restrict__ b1, const float* __restrict__ bt,
        const int* __restrict__ pidx, const int* __restrict__ mask,
        char* __restrict__ ws) {
    __bf16* w1t = (__bf16*)(ws + WS_W1T);
    __bf16* w2t = (__bf16*)(ws + WS_W2T);
    float*  b1s = (float*)(ws + WS_B1S);
    float*  bm  = (float*)(ws + WS_BIAS);
    const int blk = blockIdx.x, t = threadIdx.x;
    if (blk < 432) {                       // w1t: 110592 elems
        int idx = blk * 256 + t;
        int k = idx / 576, c = idx % 576;
        float v = w1[idx] * (c < 192 ? SCALE : 1.0f);
        w1t[c * 192 + k] = (__bf16)v;
    } else if (blk < 576) {                // w2t: 36864 elems
        int idx = (blk - 432) * 256 + t;
        int k = idx / 192, n = idx % 192;
        w2t[n * 192 + k] = (__bf16)w2[idx];
    } else if (blk < 657) {                // biasT: 20736 positions
        int idx = (blk - 576) * 256 + t;
        int m = idx / 144;                 // query
        int n = idx % 144;                 // key
        int p = pidx[idx];
        float add = (mask[idx] == 0) ? -1e9f : 0.0f;
#pragma unroll
        for (int h = 0; h < NH; ++h)
            bm[(h * 144 + n) * 144 + m] = bt[p * NH + h] + add;
    } else {                               // b1s
        for (int c = t; c < 576; c += 256)
            b1s[c] = b1[c] * (c < 192 ? SCALE : 1.0f);
    }
}

// ---------------------------------------------------------------------------
// Main: one block per b. 576 threads = 9 waves; wave w owns rows [16w,16w+16).
// X lives in per-wave A-fragments (registers). W1/W2 B-fragments read direct
// from global (L2-hot). Qs/Os and Ps are wave-private LDS (no barrier);
// only Ks/Vt are cross-wave -> 2 barriers per head.
// LDS 74.8 KB -> 2 blocks/CU (18 waves).
// ---------------------------------------------------------------------------
__global__ __launch_bounds__(576, 5) void k_attn(
        const float* __restrict__ x, const char* __restrict__ ws,
        const float* __restrict__ b2, float* __restrict__ out) {
    const __bf16* w1t = (const __bf16*)(ws + WS_W1T);
    const __bf16* w2t = (const __bf16*)(ws + WS_W2T);
    const float*  b1s = (const float*)(ws + WS_B1S);
    const float*  bmT = (const float*)(ws + WS_BIAS);

    __shared__ char smem[76544];
    __bf16* Ps = (__bf16*)(smem);            // [144][152]  wave-private
    __bf16* Qs = (__bf16*)(smem + 43776);    // [144][40]   wave-private (= Os)
    __bf16* Ks = (__bf16*)(smem + 55296);    // [144][40]   cross-wave
    __bf16* Vt = (__bf16*)(smem + 66816);    // [32][152]   cross-wave

    const int b   = blockIdx.x;
    const int tid = threadIdx.x;
    const int w   = tid >> 6;          // wave 0..8
    const int lr  = tid & 15;
    const int lg  = (tid & 63) >> 4;
    const int m0  = w * 16;
    const f32x4 zf = {0.f, 0.f, 0.f, 0.f};
    const bf16x8 zb = {(__bf16)0.f,(__bf16)0.f,(__bf16)0.f,(__bf16)0.f,
                       (__bf16)0.f,(__bf16)0.f,(__bf16)0.f,(__bf16)0.f};

    // ---- X strip -> persistent A fragments (24 VGPRs)
    bf16x8 aX[6];
    {
        const float* xr = x + ((size_t)b * SEQ + m0 + lr) * DIM + lg * 8;
#pragma unroll
        for (int kk = 0; kk < 6; ++kk) {
            f32x4 u = *(const f32x4*)(xr + kk * 32);
            f32x4 v = *(const f32x4*)(xr + kk * 32 + 4);
            bf16x8 t;
            t[0]=(__bf16)u[0]; t[1]=(__bf16)u[1]; t[2]=(__bf16)u[2]; t[3]=(__bf16)u[3];
            t[4]=(__bf16)v[0]; t[5]=(__bf16)v[1]; t[6]=(__bf16)v[2]; t[7]=(__bf16)v[3];
            aX[kk] = t;
        }
    }

    f32x4 outacc[12];
#pragma unroll
    for (int n = 0; n < 12; ++n) outacc[n] = zf;

    for (int h = 0; h < NH; ++h) {
        __syncthreads();   // Ks/Vt rewrite vs previous head's cross-wave reads

        // ---- P1: Y[strip][96] = X_strip @ W1_h^T  (B-frags from global/L2)
        f32x4 acc[6];
#pragma unroll
        for (int n = 0; n < 6; ++n) acc[n] = zf;
#pragma unroll
        for (int kk = 0; kk < 6; ++kk) {
#pragma unroll
            for (int n = 0; n < 6; ++n) {
                bf16x8 bF = *(const bf16x8*)(w1t +
                    (((n >> 1) * 192 + h * 32 + (n & 1) * 16 + lr) * 192 + kk * 32 + lg * 8));
                acc[n] = __builtin_amdgcn_mfma_f32_16x16x32_bf16(aX[kk], bF, acc[n], 0, 0, 0);
            }
        }
        // scatter to Qs / Ks / Vt
#pragma unroll
        for (int n = 0; n < 6; ++n) {
            int j = (n & 1) * 16 + lr;
            float bb = b1s[(n >> 1) * 192 + h * 32 + j];
            if (n < 2) {
#pragma unroll
                for (int r = 0; r < 4; ++r)
                    Qs[(m0 + lg * 4 + r) * 40 + j] = (__bf16)(acc[n][r] + bb);
            } else if (n < 4) {
#pragma unroll
                for (int r = 0; r < 4; ++r)
                    Ks[(m0 + lg * 4 + r) * 40 + j] = (__bf16)(acc[n][r] + bb);
            } else {
                bf16x4 pk;
#pragma unroll
                for (int r = 0; r < 4; ++r) pk[r] = (__bf16)(acc[n][r] + bb);
                *(bf16x4*)&Vt[j * 152 + m0 + lg * 4] = pk;   // [dim][key]
            }
        }
        __syncthreads();   // Ks/Vt visible to all waves

        // ---- P2: S^T = mfma(K, Q); +bias; in-register softmax; P -> Ps
        {
            bf16x8 qF = *(bf16x8*)&Qs[(m0 + lr) * 40 + lg * 8];
            f32x4 st[9];
#pragma unroll
            for (int i = 0; i < 9; ++i) {
                bf16x8 aF = *(bf16x8*)&Ks[(i * 16 + lr) * 40 + lg * 8];
                st[i] = __builtin_amdgcn_mfma_f32_16x16x32_bf16(aF, qF, zf, 0, 0, 0);
            }
            const float* bmh = bmT + h * SEQ * SEQ;
            float mx = -3.0e38f;
#pragma unroll
            for (int i = 0; i < 9; ++i)
#pragma unroll
                for (int r = 0; r < 4; ++r) {
                    st[i][r] += bmh[(i * 16 + lg * 4 + r) * 144 + m0 + lr];
                    mx = fmaxf(mx, st[i][r]);
                }
            mx = fmaxf(mx, __shfl_xor(mx, 16));
            mx = fmaxf(mx, __shfl_xor(mx, 32));
            float sum = 0.f;
#pragma unroll
            for (int i = 0; i < 9; ++i)
#pragma unroll
                for (int r = 0; r < 4; ++r) {
                    float e = __expf(st[i][r] - mx);
                    st[i][r] = e;
                    sum += e;
                }
            sum += __shfl_xor(sum, 16);
            sum += __shfl_xor(sum, 32);
            float inv = 1.f / sum;
#pragma unroll
            for (int i = 0; i < 9; ++i) {
                bf16x4 pk;
#pragma unroll
                for (int r = 0; r < 4; ++r) pk[r] = (__bf16)(st[i][r] * inv);
                *(bf16x4*)&Ps[(m0 + lr) * 152 + i * 16 + lg * 4] = pk;
            }
        }

        // ---- P3: O = P @ V  (K=144: 4 full steps + zero-composed tail)
        // no barrier: Ps is wave-private; Vt covered by barrier above
        f32x4 o0 = zf, o1 = zf;
#pragma unroll
        for (int s = 0; s < 4; ++s) {
            bf16x8 aF  = *(bf16x8*)&Ps[(m0 + lr) * 152 + s * 32 + lg * 8];
            bf16x8 b0  = *(bf16x8*)&Vt[lr * 152 + s * 32 + lg * 8];
            bf16x8 b1v = *(bf16x8*)&Vt[(16 + lr) * 152 + s * 32 + lg * 8];
            o0 = __builtin_amdgcn_mfma_f32_16x16x32_bf16(aF, b0, o0, 0, 0, 0);
            o1 = __builtin_amdgcn_mfma_f32_16x16x32_bf16(aF, b1v, o1, 0, 0, 0);
        }
        {   // tail keys 128..143: lanes lg>=2 (k>=16 of this step) supply zeros
            bf16x8 aT = zb, bT0 = zb, bT1 = zb;
            if (lg < 2) {
                aT  = *(bf16x8*)&Ps[(m0 + lr) * 152 + 128 + lg * 8];
                bT0 = *(bf16x8*)&Vt[lr * 152 + 128 + lg * 8];
                bT1 = *(bf16x8*)&Vt[(16 + lr) * 152 + 128 + lg * 8];
            }
            o0 = __builtin_amdgcn_mfma_f32_16x16x32_bf16(aT, bT0, o0, 0, 0, 0);
            o1 = __builtin_amdgcn_mfma_f32_16x16x32_bf16(aT, bT1, o1, 0, 0, 0);
        }
        __bf16* Os = Qs;   // overlay, wave-private
#pragma unroll
        for (int r = 0; r < 4; ++r) {
            Os[(m0 + lg * 4 + r) * 40 + lr]      = (__bf16)o0[r];
            Os[(m0 + lg * 4 + r) * 40 + 16 + lr] = (__bf16)o1[r];
        }

        // ---- P4: outacc += O_h @ W2_h  (B-frags from global/L2; no barrier)
        {
            bf16x8 aO = *(bf16x8*)&Os[(m0 + lr) * 40 + lg * 8];
#pragma unroll
            for (int n = 0; n < 12; ++n) {
                bf16x8 bW = *(const bf16x8*)(w2t + ((n * 16 + lr) * 192 + h * 32 + lg * 8));
                outacc[n] = __builtin_amdgcn_mfma_f32_16x16x32_bf16(aO, bW, outacc[n], 0, 0, 0);
            }
        }
    }

    // ---- epilogue: + b2, fp32 store
#pragma unroll
    for (int n = 0; n < 12; ++n) {
        int col = n * 16 + lr;
        float bb = b2[col];
#pragma unroll
        for (int r = 0; r < 4; ++r)
            out[((size_t)b * SEQ + m0 + lg * 4 + r) * DIM + col] = outacc[n][r] + bb;
    }
}

// ---------------------------------------------------------------------------
extern "C" void kernel_launch(void* const* d_in, const int* in_sizes, int n_in,
                              void* d_out, int out_size, void* d_ws, size_t ws_size,
                              hipStream_t stream) {
    const float* x    = (const float*)d_in[0];
    const float* w1   = (const float*)d_in[1];
    const float* b1   = (const float*)d_in[2];
    const float* w2   = (const float*)d_in[3];
    const float* b2   = (const float*)d_in[4];
    const float* bt   = (const float*)d_in[5];
    const int*   pidx = (const int*)d_in[6];
    const int*   mask = (const int*)d_in[7];
    float* out = (float*)d_out;
    char*  ws  = (char*)d_ws;

    k_prep<<<658, 256, 0, stream>>>(w1, w2, b1, bt, pidx, mask, ws);
    k_attn<<<BATCH, 576, 0, stream>>>(x, ws, b2, out);
}

// Round 4
// 279.243 us; speedup vs baseline: 5.0534x; 5.0534x over previous
//
#include <hip/hip_runtime.h>

#define BATCH 1024
#define SEQ   144
#define DIM   192
#define NH    6
#define HD    32
#define SCALE 0.17677669529663687f  // 1/sqrt(32)

typedef __bf16 bf16x8 __attribute__((ext_vector_type(8)));
typedef __bf16 bf16x4 __attribute__((ext_vector_type(4)));
typedef float  f32x4  __attribute__((ext_vector_type(4)));

// ---- workspace layout (bytes) ----
#define WS_W1T   0          // bf16 [576][192]  w1t[c][k] = w1[k][c] (*SCALE for c<192)
#define WS_W2T   221184     // bf16 [192][192]  w2t[n][k] = w2[k][n]
#define WS_B1S   294912     // f32  [576]       b1 (*SCALE for c<192)
#define WS_BM    297216     // bf16 [6][144][144]  bm[h][query][key] = bias + mask
#define WS_OPRE  546048     // bf16 [1024][144][192] pre-projection attention output
#define WS_NEED  (546048ull + 56623104ull)

// ---------------------------------------------------------------------------
// Prep: transpose/convert weights to bf16 B^T layout, build bf16 bias+mask.
// ---------------------------------------------------------------------------
__global__ __launch_bounds__(256) void k_prep(
        const float* __restrict__ w1, const float* __restrict__ w2,
        const float* __restrict__ b1, const float* __restrict__ bt,
        const int* __restrict__ pidx, const int* __restrict__ mask,
        char* __restrict__ ws) {
    __bf16* w1t = (__bf16*)(ws + WS_W1T);
    __bf16* w2t = (__bf16*)(ws + WS_W2T);
    float*  b1s = (float*)(ws + WS_B1S);
    __bf16* bm  = (__bf16*)(ws + WS_BM);
    const int blk = blockIdx.x, t = threadIdx.x;
    if (blk < 432) {                       // w1t: 110592 elems
        int idx = blk * 256 + t;
        int k = idx / 576, c = idx % 576;
        float v = w1[idx] * (c < 192 ? SCALE : 1.0f);
        w1t[c * 192 + k] = (__bf16)v;
    } else if (blk < 576) {                // w2t: 36864 elems
        int idx = (blk - 432) * 256 + t;
        int k = idx / 192, n = idx % 192;
        w2t[n * 192 + k] = (__bf16)w2[idx];
    } else if (blk < 657) {                // bm: 20736 (query,key) pairs
        int idx = (blk - 576) * 256 + t;   // idx = query*144 + key
        int p = pidx[idx];
        float add = (mask[idx] == 0) ? -1e9f : 0.0f;
#pragma unroll
        for (int h = 0; h < NH; ++h)
            bm[h * 20736 + idx] = (__bf16)(bt[p * NH + h] + add);
    } else {                               // b1s
        for (int c = t; c < 576; c += 256)
            b1s[c] = b1[c] * (c < 192 ? SCALE : 1.0f);
    }
}

// ---------------------------------------------------------------------------
// Attention per (b,h): 576 thr = 9 waves, wave w owns query rows [16w,16w+16).
// QKV-proj (X in regs, W1_h staged LDS) -> swapped QK^T + in-reg softmax ->
// PV with per-wave chunked P scratch -> O (bf16) to ws.  2 barriers total.
// LDS 69.5 KB -> 2 blocks/CU if VGPR <= 102.
// ---------------------------------------------------------------------------
__global__ __launch_bounds__(576, 4) void k_attn(
        const float* __restrict__ x, const char* __restrict__ ws,
        __bf16* __restrict__ opre) {
    const __bf16* w1t = (const __bf16*)(ws + WS_W1T);
    const float*  b1s = (const float*)(ws + WS_B1S);
    const __bf16* bmB = (const __bf16*)(ws + WS_BM);

    __shared__ char smem[71168];
    __bf16* Ws = (__bf16*)(smem);            // [96][200]  38400B  cross-wave
    __bf16* Ks = (__bf16*)(smem + 38400);    // [144][40]  11520B  cross-wave
    __bf16* Vt = (__bf16*)(smem + 49920);    // [32][152]   9728B  cross-wave
    __bf16* Qs = (__bf16*)(smem + 59648);    // [144][40]  11520B  wave-private
                                             // (overlaid: Q strip / P chunk / O stage)

    // XCD-chunk swizzle: 6144 = 8 * 768; keep one b's 6 head-blocks on one XCD
    const int swz = (blockIdx.x & 7) * 768 + (blockIdx.x >> 3);
    const int b = swz / NH;
    const int h = swz % NH;

    const int tid = threadIdx.x;
    const int w   = tid >> 6;
    const int lr  = tid & 15;
    const int lg  = (tid & 63) >> 4;
    const int m0  = w * 16;
    const f32x4 zf = {0.f, 0.f, 0.f, 0.f};
    const bf16x8 zb = {(__bf16)0.f,(__bf16)0.f,(__bf16)0.f,(__bf16)0.f,
                       (__bf16)0.f,(__bf16)0.f,(__bf16)0.f,(__bf16)0.f};

    // ---- stage Ws[96][200]: row r=t*32+j <- w1t[t*192+h*32+j][:]
#pragma unroll
    for (int it = 0; it < 4; ++it) {
        int idx = tid + it * 576;            // 2304 16B chunks
        int r = idx / 24, c = idx % 24;
        int tt = r >> 5, j = r & 31;
        bf16x8 v = *(const bf16x8*)(w1t + ((tt * 192 + h * 32 + j) * 192 + c * 8));
        *(bf16x8*)&Ws[r * 200 + c * 8] = v;
    }

    // ---- X strip -> A fragments (registers), overlap with Ws staging
    bf16x8 aX[6];
    {
        const float* xr = x + ((size_t)b * SEQ + m0 + lr) * DIM + lg * 8;
#pragma unroll
        for (int kk = 0; kk < 6; ++kk) {
            f32x4 u = *(const f32x4*)(xr + kk * 32);
            f32x4 v = *(const f32x4*)(xr + kk * 32 + 4);
            bf16x8 t;
            t[0]=(__bf16)u[0]; t[1]=(__bf16)u[1]; t[2]=(__bf16)u[2]; t[3]=(__bf16)u[3];
            t[4]=(__bf16)v[0]; t[5]=(__bf16)v[1]; t[6]=(__bf16)v[2]; t[7]=(__bf16)v[3];
            aX[kk] = t;
        }
    }
    __syncthreads();   // Ws visible

    // ---- P1: Y[strip][96] = X_strip @ W1_h^T ; scatter Q/K/Vt
    {
        f32x4 acc[6];
#pragma unroll
        for (int n = 0; n < 6; ++n) acc[n] = zf;
#pragma unroll
        for (int kk = 0; kk < 6; ++kk) {
#pragma unroll
            for (int n = 0; n < 6; ++n) {
                bf16x8 bF = *(bf16x8*)&Ws[(n * 16 + lr) * 200 + kk * 32 + lg * 8];
                acc[n] = __builtin_amdgcn_mfma_f32_16x16x32_bf16(aX[kk], bF, acc[n], 0, 0, 0);
            }
        }
#pragma unroll
        for (int n = 0; n < 6; ++n) {
            int j = (n & 1) * 16 + lr;
            float bb = b1s[(n >> 1) * 192 + h * 32 + j];
            if (n < 2) {
#pragma unroll
                for (int r = 0; r < 4; ++r)
                    Qs[(m0 + lg * 4 + r) * 40 + j] = (__bf16)(acc[n][r] + bb);
            } else if (n < 4) {
#pragma unroll
                for (int r = 0; r < 4; ++r)
                    Ks[(m0 + lg * 4 + r) * 40 + j] = (__bf16)(acc[n][r] + bb);
            } else {
                bf16x4 pk;
#pragma unroll
                for (int r = 0; r < 4; ++r) pk[r] = (__bf16)(acc[n][r] + bb);
                *(bf16x4*)&Vt[j * 152 + m0 + lg * 4] = pk;   // [dim][key]
            }
        }
    }
    __syncthreads();   // Ks/Vt visible

    // ---- P2: S^T = mfma(K,Q); +bias(bf16); in-register softmax
    f32x4 st[9];
    {
        bf16x8 qF = *(bf16x8*)&Qs[(m0 + lr) * 40 + lg * 8];
#pragma unroll
        for (int i = 0; i < 9; ++i) {
            bf16x8 aF = *(bf16x8*)&Ks[(i * 16 + lr) * 40 + lg * 8];
            st[i] = __builtin_amdgcn_mfma_f32_16x16x32_bf16(aF, qF, zf, 0, 0, 0);
        }
        const __bf16* bmh = bmB + h * 20736 + (m0 + lr) * 144;
        float mx = -3.0e38f;
#pragma unroll
        for (int i = 0; i < 9; ++i) {
            bf16x4 bb = *(const bf16x4*)&bmh[i * 16 + lg * 4];
#pragma unroll
            for (int r = 0; r < 4; ++r) {
                st[i][r] += (float)bb[r];
                mx = fmaxf(mx, st[i][r]);
            }
        }
        mx = fmaxf(mx, __shfl_xor(mx, 16));
        mx = fmaxf(mx, __shfl_xor(mx, 32));
        float sum = 0.f;
#pragma unroll
        for (int i = 0; i < 9; ++i)
#pragma unroll
            for (int r = 0; r < 4; ++r) {
                float e = __expf(st[i][r] - mx);
                st[i][r] = e;
                sum += e;
            }
        sum += __shfl_xor(sum, 16);
        sum += __shfl_xor(sum, 32);
        float inv = 1.f / sum;
#pragma unroll
        for (int i = 0; i < 9; ++i)
#pragma unroll
            for (int r = 0; r < 4; ++r) st[i][r] *= inv;
    }

    // ---- P3: O = P @ V via per-wave chunked P scratch (overlaid on Qs strip)
    __bf16* Pw = Qs + m0 * 40;     // [16][40] wave-private
    f32x4 o0 = zf, o1 = zf;
#pragma unroll
    for (int s = 0; s < 4; ++s) {
#pragma unroll
        for (int d = 0; d < 2; ++d) {
            int ii = 2 * s + d;
            bf16x4 pk;
#pragma unroll
            for (int r = 0; r < 4; ++r) pk[r] = (__bf16)st[ii][r];
            *(bf16x4*)&Pw[lr * 40 + d * 16 + lg * 4] = pk;
        }
        bf16x8 aP  = *(bf16x8*)&Pw[lr * 40 + lg * 8];
        bf16x8 v0F = *(bf16x8*)&Vt[lr * 152 + s * 32 + lg * 8];
        bf16x8 v1F = *(bf16x8*)&Vt[(16 + lr) * 152 + s * 32 + lg * 8];
        o0 = __builtin_amdgcn_mfma_f32_16x16x32_bf16(aP, v0F, o0, 0, 0, 0);
        o1 = __builtin_amdgcn_mfma_f32_16x16x32_bf16(aP, v1F, o1, 0, 0, 0);
    }
    {   // tail: keys 128..143 (lanes lg>=2 contribute zeros)
        bf16x4 pk;
#pragma unroll
        for (int r = 0; r < 4; ++r) pk[r] = (__bf16)st[8][r];
        *(bf16x4*)&Pw[lr * 40 + lg * 4] = pk;
        bf16x8 aP = zb, v0F = zb, v1F = zb;
        if (lg < 2) {
            aP  = *(bf16x8*)&Pw[lr * 40 + lg * 8];
            v0F = *(bf16x8*)&Vt[lr * 152 + 128 + lg * 8];
            v1F = *(bf16x8*)&Vt[(16 + lr) * 152 + 128 + lg * 8];
        }
        o0 = __builtin_amdgcn_mfma_f32_16x16x32_bf16(aP, v0F, o0, 0, 0, 0);
        o1 = __builtin_amdgcn_mfma_f32_16x16x32_bf16(aP, v1F, o1, 0, 0, 0);
    }

    // ---- O stage (coalesce) + store bf16 to ws
#pragma unroll
    for (int r = 0; r < 4; ++r) {
        Pw[(lg * 4 + r) * 40 + lr]      = (__bf16)o0[r];
        Pw[(lg * 4 + r) * 40 + 16 + lr] = (__bf16)o1[r];
    }
    {
        int l = tid & 63;
        int row = l >> 2, c = l & 3;
        bf16x8 ov = *(bf16x8*)&Pw[row * 40 + c * 8];
        *(bf16x8*)&opre[((size_t)b * SEQ + m0 + row) * DIM + h * HD + c * 8] = ov;
    }
}

// ---------------------------------------------------------------------------
// Out-projection: out[147456,192] = opre(bf16) @ w2t^T + b2.  64-row tiles.
// ---------------------------------------------------------------------------
__global__ __launch_bounds__(256, 4) void k_proj(
        const __bf16* __restrict__ opre, const char* __restrict__ ws,
        const float* __restrict__ b2, float* __restrict__ out) {
    const __bf16* w2t = (const __bf16*)(ws + WS_W2T);
    __shared__ __bf16 As[64][200];
    const int tid = threadIdx.x;
    const size_t row0 = (size_t)blockIdx.x * 64;

#pragma unroll
    for (int it = 0; it < 6; ++it) {
        int c = tid + it * 256;              // 1536 16B chunks
        int row = c / 24, off = (c % 24) * 8;
        *(bf16x8*)&As[row][off] = *(const bf16x8*)&opre[(row0 + row) * DIM + off];
    }
    __syncthreads();

    const int w  = tid >> 6;
    const int lr = tid & 15;
    const int lg = (tid & 63) >> 4;
    const f32x4 zf = {0.f, 0.f, 0.f, 0.f};
    f32x4 oa[12];
#pragma unroll
    for (int n = 0; n < 12; ++n) oa[n] = zf;

#pragma unroll
    for (int kk = 0; kk < 6; ++kk) {
        bf16x8 aF = *(bf16x8*)&As[w * 16 + lr][kk * 32 + lg * 8];
#pragma unroll
        for (int n = 0; n < 12; ++n) {
            bf16x8 bW = *(const bf16x8*)(w2t + ((n * 16 + lr) * 192 + kk * 32 + lg * 8));
            oa[n] = __builtin_amdgcn_mfma_f32_16x16x32_bf16(aF, bW, oa[n], 0, 0, 0);
        }
    }
#pragma unroll
    for (int n = 0; n < 12; ++n) {
        int col = n * 16 + lr;
        float bb = b2[col];
#pragma unroll
        for (int r = 0; r < 4; ++r)
            out[(row0 + w * 16 + lg * 4 + r) * DIM + col] = oa[n][r] + bb;
    }
}

// ---------------------------------------------------------------------------
// Fallback (ws too small for O_pre): round-2 fused kernel, bf16 bias layout.
// ---------------------------------------------------------------------------
__global__ __launch_bounds__(576, 3) void k_attn_fb(
        const float* __restrict__ x, const char* __restrict__ ws,
        const float* __restrict__ b2, float* __restrict__ out) {
    const __bf16* w1t = (const __bf16*)(ws + WS_W1T);
    const __bf16* w2t = (const __bf16*)(ws + WS_W2T);
    const float*  b1s = (const float*)(ws + WS_B1S);
    const __bf16* bmB = (const __bf16*)(ws + WS_BM);

    __shared__ char smem[144384];
    __bf16* Xs  = (__bf16*)(smem);
    __bf16* WB  = (__bf16*)(smem + 57600);
    __bf16* QO  = (__bf16*)(smem + 105984);
    __bf16* Ks  = (__bf16*)(smem + 117504);
    __bf16* VW  = (__bf16*)(smem + 129024);

    const int b   = blockIdx.x;
    const int tid = threadIdx.x;
    const int w   = tid >> 6;
    const int lr  = tid & 15;
    const int lg  = (tid & 63) >> 4;
    const int m0  = w * 16;
    const f32x4 zf = {0.f, 0.f, 0.f, 0.f};

    {
        const f32x4* x4 = (const f32x4*)(x + (size_t)b * SEQ * DIM);
#pragma unroll
        for (int it = 0; it < 12; ++it) {
            int i = tid + it * 576;
            f32x4 v = x4[i];
            int row = i / 48, col = (i % 48) * 4;
            bf16x4 pk;
            pk[0] = (__bf16)v[0]; pk[1] = (__bf16)v[1];
            pk[2] = (__bf16)v[2]; pk[3] = (__bf16)v[3];
            *(bf16x4*)&Xs[row * 200 + col] = pk;
        }
    }

    f32x4 outacc[12];
#pragma unroll
    for (int n = 0; n < 12; ++n) outacc[n] = zf;

    for (int h = 0; h < NH; ++h) {
        __syncthreads();
        {
            __bf16* Wst = WB;
#pragma unroll
            for (int it = 0; it < 4; ++it) {
                int idx = tid + it * 576;
                int r = idx / 24, c = idx % 24;
                int tt = r >> 5, j = r & 31;
                bf16x8 v = *(const bf16x8*)(w1t + ((tt * 192 + h * 32 + j) * 192 + c * 8));
                *(bf16x8*)&Wst[r * 200 + c * 8] = v;
            }
        }
        __syncthreads();
        {
            __bf16* Wst = WB;
            __bf16* Qs = QO;
            __bf16* Vt = VW;
            f32x4 acc[6];
#pragma unroll
            for (int n = 0; n < 6; ++n) acc[n] = zf;
#pragma unroll
            for (int kk = 0; kk < 6; ++kk) {
                bf16x8 aF = *(bf16x8*)&Xs[(m0 + lr) * 200 + kk * 32 + lg * 8];
#pragma unroll
                for (int n = 0; n < 6; ++n) {
                    bf16x8 bF = *(bf16x8*)&Wst[(n * 16 + lr) * 200 + kk * 32 + lg * 8];
                    acc[n] = __builtin_amdgcn_mfma_f32_16x16x32_bf16(aF, bF, acc[n], 0, 0, 0);
                }
            }
#pragma unroll
            for (int n = 0; n < 6; ++n) {
                int j = (n & 1) * 16 + lr;
                float bb = b1s[(n >> 1) * 192 + h * 32 + j];
                if (n < 2) {
#pragma unroll
                    for (int r = 0; r < 4; ++r)
                        Qs[(m0 + lg * 4 + r) * 40 + j] = (__bf16)(acc[n][r] + bb);
                } else if (n < 4) {
#pragma unroll
                    for (int r = 0; r < 4; ++r)
                        Ks[(m0 + lg * 4 + r) * 40 + j] = (__bf16)(acc[n][r] + bb);
                } else {
                    bf16x4 pk;
#pragma unroll
                    for (int r = 0; r < 4; ++r) pk[r] = (__bf16)(acc[n][r] + bb);
                    *(bf16x4*)&Vt[j * 168 + m0 + lg * 4] = pk;
                }
            }
            if (tid < 128) {
                int j = tid >> 2, c = 144 + (tid & 3) * 4;
                *(bf16x4*)&Vt[j * 168 + c] =
                    (bf16x4){(__bf16)0.f, (__bf16)0.f, (__bf16)0.f, (__bf16)0.f};
            }
        }
        __syncthreads();
        {
            __bf16* Qs = QO;
            __bf16* Ps = WB;
            bf16x8 qF = *(bf16x8*)&Qs[(m0 + lr) * 40 + lg * 8];
            f32x4 st[9];
#pragma unroll
            for (int i = 0; i < 9; ++i) {
                bf16x8 aF = *(bf16x8*)&Ks[(i * 16 + lr) * 40 + lg * 8];
                st[i] = __builtin_amdgcn_mfma_f32_16x16x32_bf16(aF, qF, zf, 0, 0, 0);
            }
            const __bf16* bmh = bmB + h * 20736 + (m0 + lr) * 144;
            float mx = -3.0e38f;
#pragma unroll
            for (int i = 0; i < 9; ++i) {
                bf16x4 bb = *(const bf16x4*)&bmh[i * 16 + lg * 4];
#pragma unroll
                for (int r = 0; r < 4; ++r) {
                    st[i][r] += (float)bb[r];
                    mx = fmaxf(mx, st[i][r]);
                }
            }
            mx = fmaxf(mx, __shfl_xor(mx, 16));
            mx = fmaxf(mx, __shfl_xor(mx, 32));
            float sum = 0.f;
#pragma unroll
            for (int i = 0; i < 9; ++i)
#pragma unroll
                for (int r = 0; r < 4; ++r) {
                    float e = __expf(st[i][r] - mx);
                    st[i][r] = e;
                    sum += e;
                }
            sum += __shfl_xor(sum, 16);
            sum += __shfl_xor(sum, 32);
            float inv = 1.f / sum;
#pragma unroll
            for (int i = 0; i < 9; ++i) {
                bf16x4 pk;
#pragma unroll
                for (int r = 0; r < 4; ++r) pk[r] = (__bf16)(st[i][r] * inv);
                *(bf16x4*)&Ps[(m0 + lr) * 168 + i * 16 + lg * 4] = pk;
            }
            *(bf16x4*)&Ps[(m0 + lr) * 168 + 144 + lg * 4] =
                (bf16x4){(__bf16)0.f, (__bf16)0.f, (__bf16)0.f, (__bf16)0.f};
        }
        __syncthreads();
        {
            __bf16* Ps = WB;
            __bf16* Vt = VW;
            __bf16* Os = QO;
            f32x4 o0 = zf, o1 = zf;
#pragma unroll
            for (int s = 0; s < 5; ++s) {
                bf16x8 aF  = *(bf16x8*)&Ps[(m0 + lr) * 168 + s * 32 + lg * 8];
                bf16x8 b0  = *(bf16x8*)&Vt[lr * 168 + s * 32 + lg * 8];
                bf16x8 b1v = *(bf16x8*)&Vt[(16 + lr) * 168 + s * 32 + lg * 8];
                o0 = __builtin_amdgcn_mfma_f32_16x16x32_bf16(aF, b0, o0, 0, 0, 0);
                o1 = __builtin_amdgcn_mfma_f32_16x16x32_bf16(aF, b1v, o1, 0, 0, 0);
            }
#pragma unroll
            for (int r = 0; r < 4; ++r) {
                Os[(m0 + lg * 4 + r) * 40 + lr]      = (__bf16)o0[r];
                Os[(m0 + lg * 4 + r) * 40 + 16 + lr] = (__bf16)o1[r];
            }
        }
        __syncthreads();
        {
            __bf16* W2s = VW;
            for (int idx = tid; idx < 768; idx += 576) {
                int row = idx >> 2, c = idx & 3;
                bf16x8 v = *(const bf16x8*)(w2t + (row * 192 + h * 32 + c * 8));
                *(bf16x8*)&W2s[row * 40 + c * 8] = v;
            }
        }
        __syncthreads();
        {
            __bf16* Os = QO;
            __bf16* W2s = VW;
            bf16x8 aO = *(bf16x8*)&Os[(m0 + lr) * 40 + lg * 8];
#pragma unroll
            for (int n = 0; n < 12; ++n) {
                bf16x8 bF = *(bf16x8*)&W2s[(n * 16 + lr) * 40 + lg * 8];
                outacc[n] = __builtin_amdgcn_mfma_f32_16x16x32_bf16(aO, bF, outacc[n], 0, 0, 0);
            }
        }
    }

#pragma unroll
    for (int n = 0; n < 12; ++n) {
        int col = n * 16 + lr;
        float bb = b2[col];
#pragma unroll
        for (int r = 0; r < 4; ++r)
            out[((size_t)b * SEQ + m0 + lg * 4 + r) * DIM + col] = outacc[n][r] + bb;
    }
}

// ---------------------------------------------------------------------------
extern "C" void kernel_launch(void* const* d_in, const int* in_sizes, int n_in,
                              void* d_out, int out_size, void* d_ws, size_t ws_size,
                              hipStream_t stream) {
    const float* x    = (const float*)d_in[0];
    const float* w1   = (const float*)d_in[1];
    const float* b1   = (const float*)d_in[2];
    const float* w2   = (const float*)d_in[3];
    const float* b2   = (const float*)d_in[4];
    const float* bt   = (const float*)d_in[5];
    const int*   pidx = (const int*)d_in[6];
    const int*   mask = (const int*)d_in[7];
    float* out = (float*)d_out;
    char*  ws  = (char*)d_ws;

    k_prep<<<658, 256, 0, stream>>>(w1, w2, b1, bt, pidx, mask, ws);
    if (ws_size >= WS_NEED) {
        __bf16* opre = (__bf16*)(ws + WS_OPRE);
        k_attn<<<BATCH * NH, 576, 0, stream>>>(x, ws, opre);
        k_proj<<<(BATCH * SEQ) / 64, 256, 0, stream>>>(opre, ws, b2, out);
    } else {
        k_attn_fb<<<BATCH, 576, 0, stream>>>(x, ws, b2, out);
    }
}